// Round 6
// baseline (283.879 us; speedup 1.0000x reference)
//
#include <hip/hip_runtime.h>
#include <hip/hip_bf16.h>
#include <math.h>

// Problem constants
#define BB 256
#define TT 512
#define EE 128
#define HH 128
#define NC 4
#define MM (BB * TT)   // 131072 rows of the input GEMM

typedef __bf16 bf16x8 __attribute__((ext_vector_type(8)));
typedef __bf16 bf16x4 __attribute__((ext_vector_type(4)));
typedef float  f32x4  __attribute__((ext_vector_type(4)));
typedef float  f32x2  __attribute__((ext_vector_type(2)));

// Branch-free tanh: 1 - 2/(1+e^{2x}) with e^{2x} = exp2(2*log2e*x).
__device__ __forceinline__ float fast_tanh(float x) {
    float t = __builtin_amdgcn_exp2f(x * 2.885390081777927f);
    return 1.f - 2.f * __builtin_amdgcn_rcpf(1.f + t);
}

// Workgroup barrier that drains ONLY the LDS counter (lgkmcnt), not vmcnt.
// __syncthreads() lowers to "s_waitcnt vmcnt(0) lgkmcnt(0); s_barrier"
// [m97 asm evidence], which puts every in-flight global load's full latency
// on the barrier path. Our barriers only order LDS traffic; global loads
// (x_proj ring refill) must stay in flight across them.
__device__ __forceinline__ void bar_lds() {
    asm volatile("s_waitcnt lgkmcnt(0)\n\ts_barrier" ::: "memory");
}

// ---------------------------------------------------------------------------
// Kernel 1: x_proj[m,h] = sum_e emb[x[m],e] * W_ih[h,e] + b_ih[h] + b_hh[h]
// Split-bf16 GEMM (AhWh + AlWh + AhWl). M-tile 64 (2048 blocks) for more
// latency-hiding parallelism on the emb gather; K in 2 halves of 64 with
// half-size LDS (54 KB -> 2 blocks/CU).
// ---------------------------------------------------------------------------
template <typename XPT>
__global__ __launch_bounds__(256, 2) void embed_gemm(
    const int* __restrict__ x, const float* __restrict__ emb,
    const float* __restrict__ Wih, const float* __restrict__ bih,
    const float* __restrict__ bhh, XPT* __restrict__ xpout)
{
    const int tid = threadIdx.x;
    const int m0  = blockIdx.x * 64;

    const int LDA = 72;  // bf16 units per 64-wide half row (144 B, 16B-aligned)
    __shared__ __bf16 Ah[64 * 72];
    __shared__ __bf16 Al[64 * 72];
    __shared__ __bf16 Wh[128 * 72];
    __shared__ __bf16 Wl[128 * 72];
    __shared__ float  bias_s[128];
    __shared__ int    gix[64];

    if (tid < 64)  gix[tid] = x[m0 + tid];
    if (tid < 128) bias_s[tid] = bih[tid] + bhh[tid];

    const int lane = tid & 63, wid = tid >> 6;
    const int col  = lane & 15, quad = lane >> 4;

    f32x4 acc[8];
#pragma unroll
    for (int nt = 0; nt < 8; ++nt) acc[nt] = f32x4{0.f, 0.f, 0.f, 0.f};

    __syncthreads();   // gix/bias visible

#pragma unroll
    for (int half = 0; half < 2; ++half) {
        // Stage W half: 128 rows x 16 float4 = 2048 chunks.
#pragma unroll
        for (int it = 0; it < 8; ++it) {
            int c   = it * 256 + tid;
            int row = c >> 4;           // 0..127
            int seg = c & 15;
            float4 wv = ((const float4*)Wih)[row * 32 + half * 16 + seg];
            bf16x4 wh, wl;
            wh[0] = (__bf16)wv.x; wl[0] = (__bf16)(wv.x - (float)wh[0]);
            wh[1] = (__bf16)wv.y; wl[1] = (__bf16)(wv.y - (float)wh[1]);
            wh[2] = (__bf16)wv.z; wl[2] = (__bf16)(wv.z - (float)wh[2]);
            wh[3] = (__bf16)wv.w; wl[3] = (__bf16)(wv.w - (float)wh[3]);
            *(bf16x4*)&Wh[row * LDA + seg * 4] = wh;
            *(bf16x4*)&Wl[row * LDA + seg * 4] = wl;
        }
        // Stage A half: 64 gathered rows x 16 float4 = 1024 chunks.
#pragma unroll
        for (int it = 0; it < 4; ++it) {
            int c   = it * 256 + tid;
            int row = c >> 4;           // 0..63
            int seg = c & 15;
            int gi  = gix[row];
            float4 av = ((const float4*)emb)[(size_t)gi * 32 + half * 16 + seg];
            bf16x4 ah, al;
            ah[0] = (__bf16)av.x; al[0] = (__bf16)(av.x - (float)ah[0]);
            ah[1] = (__bf16)av.y; al[1] = (__bf16)(av.y - (float)ah[1]);
            ah[2] = (__bf16)av.z; al[2] = (__bf16)(av.z - (float)ah[2]);
            ah[3] = (__bf16)av.w; al[3] = (__bf16)(av.w - (float)ah[3]);
            *(bf16x4*)&Ah[row * LDA + seg * 4] = ah;
            *(bf16x4*)&Al[row * LDA + seg * 4] = al;
        }
        __syncthreads();   // staged data visible

#pragma unroll
        for (int kk = 0; kk < 2; ++kk) {  // K steps of 32 within the half
            int ra = (wid * 16 + col) * LDA + kk * 32 + quad * 8;
            bf16x8 afh = *(const bf16x8*)&Ah[ra];
            bf16x8 afl = *(const bf16x8*)&Al[ra];
#pragma unroll
            for (int nt = 0; nt < 8; ++nt) {
                int ro = (nt * 16 + col) * LDA + kk * 32 + quad * 8;
                bf16x8 wfh = *(const bf16x8*)&Wh[ro];
                bf16x8 wfl = *(const bf16x8*)&Wl[ro];
                acc[nt] = __builtin_amdgcn_mfma_f32_16x16x32_bf16(afh, wfh, acc[nt], 0, 0, 0);
                acc[nt] = __builtin_amdgcn_mfma_f32_16x16x32_bf16(afl, wfh, acc[nt], 0, 0, 0);
                acc[nt] = __builtin_amdgcn_mfma_f32_16x16x32_bf16(afh, wfl, acc[nt], 0, 0, 0);
            }
        }
        if (half == 0) __syncthreads();   // MFMA reads done before restage
    }

    // Epilogue: C/D layout col=lane&15, row=(lane>>4)*4+reg  [verified m89/m91]
#pragma unroll
    for (int nt = 0; nt < 8; ++nt) {
        int m = m0 + wid * 16 + quad * 4;
        int n = nt * 16 + col;
        float bs = bias_s[n];
#pragma unroll
        for (int r = 0; r < 4; ++r)
            xpout[(size_t)(m + r) * 128 + n] = (XPT)(acc[nt][r] + bs);
    }
}

// ---------------------------------------------------------------------------
// Kernel 2: sequential scan  h = tanh(x_proj[t] + W_hh @ h)   (512 steps)
// One block per batch element (256 blocks = 1/CU), 256 threads = 4 waves.
// Wave q owns K-slice [32q,32q+32); lane l computes outputs {l, l+64}.
// Barriers drain lgkmcnt ONLY (bar_lds) so the x_proj ring-refill global
// loads stay in flight across steps instead of being vmcnt(0)-drained at
// every __syncthreads. Weight pin re-asserted inside the loop.
// ---------------------------------------------------------------------------
template <typename XPT>
__global__ __launch_bounds__(256, 1) void rnn_scan(
    const XPT* __restrict__ xp, const float* __restrict__ Whh,
    const float* __restrict__ h0, float* __restrict__ hlast)
{
    const int b    = blockIdx.x;
    const int tid  = threadIdx.x;
    const int q    = tid >> 6;       // wave id = K-slice
    const int lane = tid & 63;

    __shared__ float h_s[128];
    __shared__ float part[4 * 128];

    // Weights: rows lane and lane+64, K-slice [32q, 32q+32), as float4s.
    f32x4 wA[8], wB[8];
    {
        const float* r0 = Whh + (size_t)lane * 128 + q * 32;
        const float* r1 = Whh + (size_t)(lane + 64) * 128 + q * 32;
#pragma unroll
        for (int c = 0; c < 8; ++c) {
            wA[c] = *(const f32x4*)(r0 + c * 4);
            wB[c] = *(const f32x4*)(r1 + c * 4);
        }
    }

    if (tid < 128) h_s[tid] = h0[b * 128 + tid];

    // x_proj register ring: 8 steps ahead (threads 0..127 only)
    const XPT* xpb = xp + (size_t)b * (TT * 128);
    float xv[8];
#pragma unroll
    for (int s = 0; s < 8; ++s)
        xv[s] = (tid < 128) ? (float)xpb[s * 128 + tid] : 0.f;
    bar_lds();

    for (int tw = 0; tw < TT; tw += 8) {
        // Re-assert weight residency each window: asm results can't be
        // rematerialized and the in-loop use blocks sinking the loads.
        asm volatile("" : "+v"(wA[0]), "+v"(wA[1]), "+v"(wA[2]), "+v"(wA[3]),
                          "+v"(wA[4]), "+v"(wA[5]), "+v"(wA[6]), "+v"(wA[7]),
                          "+v"(wB[0]), "+v"(wB[1]), "+v"(wB[2]), "+v"(wB[3]),
                          "+v"(wB[4]), "+v"(wB[5]), "+v"(wB[6]), "+v"(wB[7]));
#pragma unroll
        for (int ts = 0; ts < 8; ++ts) {
            // broadcast reads of this wave's h slice (8 ds_read_b128)
            const float* hq = &h_s[q * 32];
            f32x4 h4[8];
#pragma unroll
            for (int u = 0; u < 8; ++u) h4[u] = *(const f32x4*)&hq[u * 4];

            f32x4 aA = f32x4{0.f, 0.f, 0.f, 0.f};
            f32x4 aB = f32x4{0.f, 0.f, 0.f, 0.f};
#pragma unroll
            for (int u = 0; u < 8; ++u) {
                aA += wA[u] * h4[u];
                aB += wB[u] * h4[u];
            }
            part[q * 128 + lane]      = (aA[0] + aA[1]) + (aA[2] + aA[3]);
            part[q * 128 + 64 + lane] = (aB[0] + aB[1]) + (aB[2] + aB[3]);
            bar_lds();
            if (tid < 128) {
                float s = (part[tid] + part[128 + tid])
                        + (part[256 + tid] + part[384 + tid]);
                h_s[tid] = fast_tanh(s + xv[ts]);
                // refill ring slot for step tw+8+ts (stays in flight; no
                // vmcnt drain at the barrier below)
                if (tw + 8 < TT)
                    xv[ts] = (float)xpb[(size_t)(tw + 8 + ts) * 128 + tid];
            }
            bar_lds();
        }
    }
    if (tid < 128) hlast[b * 128 + tid] = h_s[tid];
}

// ---------------------------------------------------------------------------
// Kernel 3: MLP head. hidden = relu(h @ W1^T + b1) [256]; logits = hidden @ W2^T + b2 [4]
// One block per batch row. Also writes last_hidden to d_out.
// ---------------------------------------------------------------------------
__global__ __launch_bounds__(256, 2) void mlp_head(
    const float* __restrict__ hlast, const float* __restrict__ W1,
    const float* __restrict__ b1, const float* __restrict__ W2,
    const float* __restrict__ b2, float* __restrict__ out)
{
    const int b = blockIdx.x, tid = threadIdx.x;
    __shared__ float h_row[128];
    __shared__ float hid[256];

    if (tid < 128) {
        float hv = hlast[b * 128 + tid];
        h_row[tid] = hv;
        out[1024 + b * 128 + tid] = hv;   // last_hidden output (fp32)
    }
    __syncthreads();

    // hidden[tid] = relu(b1[tid] + sum_k W1[tid][k] * h[k]); W1 from L2
    {
        float acc = b1[tid];
        const float4* wrow = (const float4*)(W1 + (size_t)tid * 128);
#pragma unroll
        for (int k4 = 0; k4 < 32; ++k4) {
            float4 wv = wrow[k4];
            acc += wv.x * h_row[k4 * 4 + 0] + wv.y * h_row[k4 * 4 + 1]
                 + wv.z * h_row[k4 * 4 + 2] + wv.w * h_row[k4 * 4 + 3];
        }
        hid[tid] = fmaxf(acc, 0.f);
    }
    __syncthreads();

    // logits: wave w -> class w; 64-lane strided partials + shuffle reduce
    const int wv = tid >> 6, lane = tid & 63;
    float s = 0.f;
#pragma unroll
    for (int qq = 0; qq < 4; ++qq)
        s += hid[qq * 64 + lane] * W2[wv * 256 + qq * 64 + lane];
#pragma unroll
    for (int off = 32; off > 0; off >>= 1) s += __shfl_down(s, off);
    if (lane == 0) out[b * 4 + wv] = s + b2[wv];
}

// ---------------------------------------------------------------------------
extern "C" void kernel_launch(void* const* d_in, const int* in_sizes, int n_in,
                              void* d_out, int out_size, void* d_ws, size_t ws_size,
                              hipStream_t stream)
{
    const int*   x   = (const int*)d_in[0];
    const float* h0  = (const float*)d_in[1];
    const float* emb = (const float*)d_in[2];
    const float* Wih = (const float*)d_in[3];
    const float* Whh = (const float*)d_in[4];
    const float* bih = (const float*)d_in[5];
    const float* bhh = (const float*)d_in[6];
    const float* W1  = (const float*)d_in[7];
    const float* b1  = (const float*)d_in[8];
    const float* W2  = (const float*)d_in[9];
    const float* b2  = (const float*)d_in[10];
    float* out = (float*)d_out;

    const size_t xp_f32_bytes = (size_t)MM * 128 * sizeof(float);   // 64 MB
    const size_t hl_bytes     = (size_t)BB * 128 * sizeof(float);   // 128 KB

    if (ws_size >= xp_f32_bytes + hl_bytes) {
        float* xpw = (float*)d_ws;
        float* hl  = (float*)((char*)d_ws + xp_f32_bytes);
        embed_gemm<float><<<MM / 64, 256, 0, stream>>>(x, emb, Wih, bih, bhh, xpw);
        rnn_scan<float><<<BB, 256, 0, stream>>>(xpw, Whh, h0, hl);
        mlp_head<<<BB, 256, 0, stream>>>(hl, W1, b1, W2, b2, out);
    } else {
        // Fallback: bf16 x_proj storage (32 MB) if workspace is small
        __bf16* xpw = (__bf16*)d_ws;
        float*  hl  = (float*)((char*)d_ws + (size_t)MM * 128 * sizeof(__bf16));
        embed_gemm<__bf16><<<MM / 64, 256, 0, stream>>>(x, emb, Wih, bih, bhh, xpw);
        rnn_scan<__bf16><<<BB, 256, 0, stream>>>(xpw, Whh, h0, hl);
        mlp_head<<<BB, 256, 0, stream>>>(hl, W1, b1, W2, b2, out);
    }
}

// Round 7
// 276.776 us; speedup vs baseline: 1.0257x; 1.0257x over previous
//
#include <hip/hip_runtime.h>
#include <hip/hip_bf16.h>
#include <math.h>

// Problem constants
#define BB 256
#define TT 512
#define EE 128
#define HH 128
#define NC 4
#define MM (BB * TT)   // 131072 rows of the input GEMM

typedef __bf16 bf16x8 __attribute__((ext_vector_type(8)));
typedef __bf16 bf16x4 __attribute__((ext_vector_type(4)));
typedef float  f32x4  __attribute__((ext_vector_type(4)));

// Branch-free tanh: 1 - 2/(1+e^{2x}) with e^{2x} = exp2(2*log2e*x).
__device__ __forceinline__ float fast_tanh(float x) {
    float t = __builtin_amdgcn_exp2f(x * 2.885390081777927f);
    return 1.f - 2.f * __builtin_amdgcn_rcpf(1.f + t);
}

// ---------------------------------------------------------------------------
// Kernel 1 (v3): x_proj[m,h] = sum_e emb[x[m],e]*W_ih[h,e] + b_ih[h] + b_hh[h]
// - W split hi/lo once per block into LDS (18 KB x2), K in 2 halves of 64.
// - A (gathered emb rows) goes DIRECTLY global -> MFMA A-fragment registers
//   with on-the-fly hi/lo split: A-frag lane layout is A[m=lane&15][k=quad*8+j],
//   i.e. 8 consecutive floats = 2 dwordx4 per lane. No A-LDS, no A barrier.
// - Coalesced epilogue: C-frags -> LDS (reusing the W buffers) -> float4 rows.
// Block tile: M=64 (wave m-tile 16), N=128, K=128. Grid 2048.
// ---------------------------------------------------------------------------
template <typename XPT>
__global__ __launch_bounds__(256, 3) void embed_gemm(
    const int* __restrict__ x, const float* __restrict__ emb,
    const float* __restrict__ Wih, const float* __restrict__ bih,
    const float* __restrict__ bhh, XPT* __restrict__ xpout)
{
    const int tid = threadIdx.x;
    const int m0  = blockIdx.x * 64;

    const int LDW = 72;   // bf16 units per 64-wide K-half row (144 B)
    const int LDE = 132;  // f32 units per epilogue row (64 rows x 132)
    __shared__ __align__(16) char smem[36864 + 512];
    __bf16* Wh     = (__bf16*)smem;             // [128*72] = 18432 B
    __bf16* Wl     = (__bf16*)(smem + 18432);   // [128*72]
    float*  epi    = (float*)smem;              // reuse: [64*132] = 33792 B
    float*  bias_s = (float*)(smem + 36864);    // [128]

    if (tid < 128) bias_s[tid] = bih[tid] + bhh[tid];

    const int lane = tid & 63, wid = tid >> 6;
    const int col  = lane & 15, quad = lane >> 4;

    // Per-lane gather index for this lane's A rows (m = m0 + wid*16 + col).
    const int gi = x[m0 + wid * 16 + col];
    const float* arow = emb + (size_t)gi * 128;

    f32x4 acc[8];
#pragma unroll
    for (int nt = 0; nt < 8; ++nt) acc[nt] = f32x4{0.f, 0.f, 0.f, 0.f};

#pragma unroll
    for (int half = 0; half < 2; ++half) {
        // Stage W K-half, split hi/lo: 128 rows x 16 float4.
#pragma unroll
        for (int it = 0; it < 8; ++it) {
            int c   = it * 256 + tid;   // 0..2047
            int row = c >> 4;           // 0..127
            int seg = c & 15;
            float4 wv = ((const float4*)Wih)[row * 32 + half * 16 + seg];
            bf16x4 wh, wl;
            wh[0] = (__bf16)wv.x; wl[0] = (__bf16)(wv.x - (float)wh[0]);
            wh[1] = (__bf16)wv.y; wl[1] = (__bf16)(wv.y - (float)wh[1]);
            wh[2] = (__bf16)wv.z; wl[2] = (__bf16)(wv.z - (float)wh[2]);
            wh[3] = (__bf16)wv.w; wl[3] = (__bf16)(wv.w - (float)wh[3]);
            *(bf16x4*)&Wh[row * LDW + seg * 4] = wh;
            *(bf16x4*)&Wl[row * LDW + seg * 4] = wl;
        }
        __syncthreads();   // W staged (also covers bias_s on half 0)

#pragma unroll
        for (int kk = 0; kk < 2; ++kk) {  // K steps of 32 within the half
            // A-fragment direct from global: 8 consecutive f32, split hi/lo.
            const float* ap = arow + half * 64 + kk * 32 + quad * 8;
            f32x4 a0 = *(const f32x4*)ap;
            f32x4 a1 = *(const f32x4*)(ap + 4);
            bf16x8 afh, afl;
#pragma unroll
            for (int u = 0; u < 4; ++u) {
                afh[u]     = (__bf16)a0[u]; afl[u]     = (__bf16)(a0[u] - (float)afh[u]);
                afh[u + 4] = (__bf16)a1[u]; afl[u + 4] = (__bf16)(a1[u] - (float)afh[u + 4]);
            }
#pragma unroll
            for (int nt = 0; nt < 8; ++nt) {
                int ro = (nt * 16 + col) * LDW + kk * 32 + quad * 8;
                bf16x8 wfh = *(const bf16x8*)&Wh[ro];
                bf16x8 wfl = *(const bf16x8*)&Wl[ro];
                acc[nt] = __builtin_amdgcn_mfma_f32_16x16x32_bf16(afh, wfh, acc[nt], 0, 0, 0);
                acc[nt] = __builtin_amdgcn_mfma_f32_16x16x32_bf16(afl, wfh, acc[nt], 0, 0, 0);
                acc[nt] = __builtin_amdgcn_mfma_f32_16x16x32_bf16(afh, wfl, acc[nt], 0, 0, 0);
            }
        }
        __syncthreads();   // MFMA LDS reads done before restage / epi reuse
    }

    // Epilogue: C/D layout col=lane&15, row=quad*4+reg [verified m89/m91].
    // Write bias-added tile to LDS (epi), then store coalesced float4 rows.
#pragma unroll
    for (int nt = 0; nt < 8; ++nt) {
        int n = nt * 16 + col;
        float bs = bias_s[n];
#pragma unroll
        for (int r = 0; r < 4; ++r)
            epi[(wid * 16 + quad * 4 + r) * LDE + n] = acc[nt][r] + bs;
    }
    __syncthreads();

#pragma unroll
    for (int it = 0; it < 8; ++it) {
        int c   = it * 256 + tid;  // 0..2047 float4 chunks of the 64x128 tile
        int row = c >> 5;          // 0..63
        int cf  = c & 31;          // float4 col
        f32x4 v = *(const f32x4*)&epi[row * LDE + cf * 4];
        if (sizeof(XPT) == 4) {
            *(f32x4*)&((float*)xpout)[(size_t)(m0 + row) * 128 + cf * 4] = v;
        } else {
            bf16x4 bv;
            bv[0] = (__bf16)v[0]; bv[1] = (__bf16)v[1];
            bv[2] = (__bf16)v[2]; bv[3] = (__bf16)v[3];
            *(bf16x4*)&((__bf16*)xpout)[(size_t)(m0 + row) * 128 + cf * 4] = bv;
        }
    }
}

// ---------------------------------------------------------------------------
// Kernel 2: sequential scan  h = tanh(x_proj[t] + W_hh @ h)   (512 steps)
// EXACT round-5 configuration (best measured: 168 us): one pre-loop pin,
// plain __syncthreads, f32x4 weights/reads, 8-deep register x_proj ring.
// ---------------------------------------------------------------------------
template <typename XPT>
__global__ __launch_bounds__(256, 1) void rnn_scan(
    const XPT* __restrict__ xp, const float* __restrict__ Whh,
    const float* __restrict__ h0, float* __restrict__ hlast)
{
    const int b    = blockIdx.x;
    const int tid  = threadIdx.x;
    const int q    = tid >> 6;       // wave id = K-slice
    const int lane = tid & 63;

    __shared__ float h_s[128];
    __shared__ float part[4 * 128];

    // Weights: rows lane and lane+64, K-slice [32q, 32q+32), as float4s.
    f32x4 wA[8], wB[8];
    {
        const float* r0 = Whh + (size_t)lane * 128 + q * 32;
        const float* r1 = Whh + (size_t)(lane + 64) * 128 + q * 32;
#pragma unroll
        for (int c = 0; c < 8; ++c) {
            wA[c] = *(const f32x4*)(r0 + c * 4);
            wB[c] = *(const f32x4*)(r1 + c * 4);
        }
    }
    // Pin once: asm result cannot be rematerialized.
#pragma unroll
    for (int c = 0; c < 8; ++c)
        asm volatile("" : "+v"(wA[c]), "+v"(wB[c]));

    if (tid < 128) h_s[tid] = h0[b * 128 + tid];

    // x_proj register ring: 8 steps ahead (threads 0..127 only)
    const XPT* xpb = xp + (size_t)b * (TT * 128);
    float xv[8];
#pragma unroll
    for (int s = 0; s < 8; ++s)
        xv[s] = (tid < 128) ? (float)xpb[s * 128 + tid] : 0.f;
    __syncthreads();

    for (int tw = 0; tw < TT; tw += 8) {
#pragma unroll
        for (int ts = 0; ts < 8; ++ts) {
            // broadcast reads of this wave's h slice (8 ds_read_b128)
            const float* hq = &h_s[q * 32];
            f32x4 h4[8];
#pragma unroll
            for (int u = 0; u < 8; ++u) h4[u] = *(const f32x4*)&hq[u * 4];

            f32x4 aA = f32x4{0.f, 0.f, 0.f, 0.f};
            f32x4 aB = f32x4{0.f, 0.f, 0.f, 0.f};
#pragma unroll
            for (int u = 0; u < 8; ++u) {
                aA += wA[u] * h4[u];
                aB += wB[u] * h4[u];
            }
            part[q * 128 + lane]      = (aA[0] + aA[1]) + (aA[2] + aA[3]);
            part[q * 128 + 64 + lane] = (aB[0] + aB[1]) + (aB[2] + aB[3]);
            __syncthreads();
            if (tid < 128) {
                float s = (part[tid] + part[128 + tid])
                        + (part[256 + tid] + part[384 + tid]);
                h_s[tid] = fast_tanh(s + xv[ts]);
                if (tw + 8 < TT)
                    xv[ts] = (float)xpb[(size_t)(tw + 8 + ts) * 128 + tid];
            }
            __syncthreads();
        }
    }
    if (tid < 128) hlast[b * 128 + tid] = h_s[tid];
}

// ---------------------------------------------------------------------------
// Kernel 3: MLP head. hidden = relu(h @ W1^T + b1) [256]; logits = hidden @ W2^T + b2 [4]
// One block per batch row. Also writes last_hidden to d_out.
// ---------------------------------------------------------------------------
__global__ __launch_bounds__(256, 2) void mlp_head(
    const float* __restrict__ hlast, const float* __restrict__ W1,
    const float* __restrict__ b1, const float* __restrict__ W2,
    const float* __restrict__ b2, float* __restrict__ out)
{
    const int b = blockIdx.x, tid = threadIdx.x;
    __shared__ float h_row[128];
    __shared__ float hid[256];

    if (tid < 128) {
        float hv = hlast[b * 128 + tid];
        h_row[tid] = hv;
        out[1024 + b * 128 + tid] = hv;   // last_hidden output (fp32)
    }
    __syncthreads();

    {
        float acc = b1[tid];
        const float4* wrow = (const float4*)(W1 + (size_t)tid * 128);
#pragma unroll
        for (int k4 = 0; k4 < 32; ++k4) {
            float4 wv = wrow[k4];
            acc += wv.x * h_row[k4 * 4 + 0] + wv.y * h_row[k4 * 4 + 1]
                 + wv.z * h_row[k4 * 4 + 2] + wv.w * h_row[k4 * 4 + 3];
        }
        hid[tid] = fmaxf(acc, 0.f);
    }
    __syncthreads();

    const int wv = tid >> 6, lane = tid & 63;
    float s = 0.f;
#pragma unroll
    for (int qq = 0; qq < 4; ++qq)
        s += hid[qq * 64 + lane] * W2[wv * 256 + qq * 64 + lane];
#pragma unroll
    for (int off = 32; off > 0; off >>= 1) s += __shfl_down(s, off);
    if (lane == 0) out[b * 4 + wv] = s + b2[wv];
}

// ---------------------------------------------------------------------------
extern "C" void kernel_launch(void* const* d_in, const int* in_sizes, int n_in,
                              void* d_out, int out_size, void* d_ws, size_t ws_size,
                              hipStream_t stream)
{
    const int*   x   = (const int*)d_in[0];
    const float* h0  = (const float*)d_in[1];
    const float* emb = (const float*)d_in[2];
    const float* Wih = (const float*)d_in[3];
    const float* Whh = (const float*)d_in[4];
    const float* bih = (const float*)d_in[5];
    const float* bhh = (const float*)d_in[6];
    const float* W1  = (const float*)d_in[7];
    const float* b1  = (const float*)d_in[8];
    const float* W2  = (const float*)d_in[9];
    const float* b2  = (const float*)d_in[10];
    float* out = (float*)d_out;

    const size_t xp_f32_bytes = (size_t)MM * 128 * sizeof(float);   // 64 MB
    const size_t hl_bytes     = (size_t)BB * 128 * sizeof(float);   // 128 KB

    if (ws_size >= xp_f32_bytes + hl_bytes) {
        float* xpw = (float*)d_ws;
        float* hl  = (float*)((char*)d_ws + xp_f32_bytes);
        embed_gemm<float><<<MM / 64, 256, 0, stream>>>(x, emb, Wih, bih, bhh, xpw);
        rnn_scan<float><<<BB, 256, 0, stream>>>(xpw, Whh, h0, hl);
        mlp_head<<<BB, 256, 0, stream>>>(hl, W1, b1, W2, b2, out);
    } else {
        // Fallback: bf16 x_proj storage (32 MB) if workspace is small
        __bf16* xpw = (__bf16*)d_ws;
        float*  hl  = (float*)((char*)d_ws + (size_t)MM * 128 * sizeof(__bf16));
        embed_gemm<__bf16><<<MM / 64, 256, 0, stream>>>(x, emb, Wih, bih, bhh, xpw);
        rnn_scan<__bf16><<<BB, 256, 0, stream>>>(xpw, Whh, h0, hl);
        mlp_head<<<BB, 256, 0, stream>>>(hl, W1, b1, W2, b2, out);
    }
}